// Round 6
// baseline (288.721 us; speedup 1.0000x reference)
//
#include <hip/hip_runtime.h>

// B=8, C=64, H=256, W=256
#define BB 8
#define CC 64
#define HH 256
#define WW 256
#define HW (HH*WW)

typedef __attribute__((ext_vector_type(8))) short bf16x8;
typedef __attribute__((ext_vector_type(4))) float f32x4;

__device__ __forceinline__ int reflect_idx(int v, int n) {
    if (v < 0) v = -v;
    if (v >= n) v = 2*n - 2 - v;
    return v;
}

// f32 -> bf16 (RNE) raw bits
__device__ __forceinline__ short f2bf(float f) {
    union { float f; unsigned u; } x; x.f = f;
    unsigned r = (x.u + 0x7fffu + ((x.u >> 16) & 1u)) >> 16;
    return (short)r;
}

__device__ __forceinline__ unsigned cvt_pk_bf16(float lo, float hi) {
    unsigned r;
    asm("v_cvt_pk_bf16_f32 %0, %1, %2" : "=v"(r) : "v"(lo), "v"(hi));
    return r;
}

// swizzled word offset in a wave's p-buffer: pos in [0,108), quad q in [0,4)
// stride 16 words, 16B-unit XOR swizzle -> b128 accesses are 2-way max (optimal)
__device__ __forceinline__ int pofs(int pos, int q) {
    return pos * 16 + ((q ^ (pos & 3) ^ ((pos >> 2) & 3)) << 2);
}

__global__ __launch_bounds__(256, 3)
void corr_v6_kernel(const float* __restrict__ hs,
                    const float* __restrict__ refLR,
                    const float* __restrict__ w_first,
                    const float* __restrict__ b_first,
                    const float* __restrict__ w_fuse,
                    const float* __restrict__ b_fuse,
                    float* __restrict__ out)
{
    // s_w: bf16 w_fuse, quad-interleaved k-order (k' = g*32 + q*8 + j):
    //      j<4 -> att col (g*16+q*4+j), j>=4 -> hs col (64+g*16+q*4+j-4)
    __shared__ short s_w[64 * 136];        // 17408 B
    __shared__ float s_bf[64];             // 256 B
    __shared__ float s_p[4][108 * 16];     // 4 x 6912 B wave-private p (swizzled)
                                           // total 45312 B -> 3 blocks/CU

    const int t = threadIdx.x;
    const int wv = t >> 6, lane = t & 63;
    const int cl = lane & 15, kb = lane >> 4;    // x-in-strip, channel-quad

    // XCD swizzle: each XCD owns one batch image
    const int d = (int)blockIdx.x;
    const int lid = (d & 7) * 256 + (d >> 3);
    const int b = lid >> 8;
    const int rr = lid & 255;
    const int by = rr >> 2, bx = rr & 3;         // 64 y-tiles(4 rows) x 4 x-tiles(64)
    const int y0 = by * 4;
    const int x0 = bx * 64 + wv * 16;            // wave: 4 rows x 16 cols

    // ---- stage weights + bias ----
    #pragma unroll
    for (int rep = 0; rep < 32; ++rep) {
        int idx = t + rep * 256;                 // m*128 + k'
        int m = idx >> 7, k = idx & 127;
        int g = k >> 5, r2 = k & 31, q = r2 >> 3, j = r2 & 7;
        int col = (j < 4) ? (g*16 + q*4 + j) : (64 + g*16 + q*4 + j - 4);
        s_w[m * 136 + k] = f2bf(w_fuse[m * 128 + col]);
    }
    if (t < 64) s_bf[t] = b_fuse[t];
    __syncthreads();   // only block barrier

    // ---- halo: 6 rows x 18 cols = 108 positions; slot0=lane, slot1=64+lane (lane<44) ----
    const int p0y = lane / 18, p0x = lane % 18;
    const bool has1 = lane < 44;
    const int p1i = 64 + lane;
    const int p1y = p1i / 18, p1x = p1i % 18;
    const int gof0 = reflect_idx(y0 - 1 + p0y, HH) * WW + reflect_idx(x0 - 1 + p0x, WW);
    const int g1t  = reflect_idx(y0 - 1 + p1y, HH) * WW + reflect_idx(x0 - 1 + p1x, WW);
    const int gof1 = has1 ? g1t : gof0;

    // refLR halo values: loaded once, reused across all 4 groups
    const float* rbase = refLR + (size_t)b * 9 * HW;
    float rin0[9], rin1[9];
    #pragma unroll
    for (int j = 0; j < 9; ++j) {
        rin0[j] = rbase[(size_t)j * HW + gof0];
        rin1[j] = rbase[(size_t)j * HW + gof1];
    }

    const float* hsb = hs + (size_t)b * CC * HW;
    float* const sp = s_p[wv];

    // prefetch group-0 hs halo values (one channel plane per instruction)
    float h0c[16], h1c[16];
    #pragma unroll
    for (int i = 0; i < 16; ++i) {
        h0c[i] = hsb[(size_t)i * HW + gof0];
        h1c[i] = hsb[(size_t)i * HW + gof1];
    }

    f32x4 acc[4][4];
    #pragma unroll
    for (int nt = 0; nt < 4; ++nt)
        #pragma unroll
        for (int mt = 0; mt < 4; ++mt) acc[nt][mt] = (f32x4){0.f, 0.f, 0.f, 0.f};

    const int gcn0 = y0 * WW + x0 + cl;          // center pixel base (nt=0)

    #pragma unroll 1
    for (int g = 0; g < 4; ++g) {
        // ---- conv phase (lane = halo position): ref 1x1 conv + leaky, p = hs*ref ----
        #pragma unroll
        for (int q = 0; q < 4; ++q) {
            f32x4 pv;
            #pragma unroll
            for (int c4 = 0; c4 < 4; ++c4) {
                const int c = g*16 + q*4 + c4;
                float v = b_first[c];                         // wave-uniform s_load
                #pragma unroll
                for (int j = 0; j < 9; ++j)
                    v = fmaf(w_first[c*9 + j], rin0[j], v);
                v = v > 0.f ? v : 0.1f * v;
                pv[c4] = h0c[q*4 + c4] * v;
            }
            *(f32x4*)&sp[pofs(lane, q)] = pv;
        }
        if (has1) {
            #pragma unroll
            for (int q = 0; q < 4; ++q) {
                f32x4 pv;
                #pragma unroll
                for (int c4 = 0; c4 < 4; ++c4) {
                    const int c = g*16 + q*4 + c4;
                    float v = b_first[c];
                    #pragma unroll
                    for (int j = 0; j < 9; ++j)
                        v = fmaf(w_first[c*9 + j], rin1[j], v);
                    v = v > 0.f ? v : 0.1f * v;
                    pv[c4] = h1c[q*4 + c4] * v;
                }
                *(f32x4*)&sp[pofs(p1i, q)] = pv;
            }
        }

        // prefetch next group's hs halo (h regs dead after conv; ~700cyc to next use)
        if (g < 3) {
            #pragma unroll
            for (int i = 0; i < 16; ++i) {
                h0c[i] = hsb[(size_t)((g+1)*16 + i) * HW + gof0];
                h1c[i] = hsb[(size_t)((g+1)*16 + i) * HW + gof1];
            }
        }

        // center hs for gating/B-frag (L2-hot; issued before box phase hides latency)
        float cen[16];
        #pragma unroll
        for (int nt = 0; nt < 4; ++nt)
            #pragma unroll
            for (int c4 = 0; c4 < 4; ++c4)
                cen[nt*4 + c4] = hsb[(size_t)(g*16 + kb*4 + c4) * HW + gcn0 + nt * WW];

        // ---- pixel phase (lane = (cl,kb)): box-sum, sigmoid, MFMA ----
        #pragma unroll
        for (int nt = 0; nt < 4; ++nt) {
            f32x4 cr = (f32x4){0.f, 0.f, 0.f, 0.f};
            #pragma unroll
            for (int dy = 0; dy < 3; ++dy)
                #pragma unroll
                for (int dx = 0; dx < 3; ++dx)
                    cr += *(const f32x4*)&sp[pofs((nt + dy) * 18 + cl + dx, kb)];

            float av[4];
            #pragma unroll
            for (int c4 = 0; c4 < 4; ++c4)
                av[c4] = __builtin_amdgcn_rcpf(
                    1.0f + __builtin_amdgcn_exp2f(cr[c4] * -1.44269504088896f)) * cen[nt*4 + c4];

            union { unsigned u[4]; bf16x8 v; } bfr;
            bfr.u[0] = cvt_pk_bf16(av[0], av[1]);
            bfr.u[1] = cvt_pk_bf16(av[2], av[3]);
            bfr.u[2] = cvt_pk_bf16(cen[nt*4 + 0], cen[nt*4 + 1]);
            bfr.u[3] = cvt_pk_bf16(cen[nt*4 + 2], cen[nt*4 + 3]);

            #pragma unroll
            for (int mt = 0; mt < 4; ++mt) {
                const bf16x8 af = *(const bf16x8*)&s_w[(mt*16 + cl) * 136 + g*32 + kb*8];
                acc[nt][mt] = __builtin_amdgcn_mfma_f32_16x16x32_bf16(af, bfr.v, acc[nt][mt], 0, 0, 0);
            }
        }
    }

    // ---- epilogue: fully-coalesced 64B stores per (o, row) ----
    float* const ob = out + (size_t)b * CC * HW;
    #pragma unroll
    for (int mt = 0; mt < 4; ++mt) {
        #pragma unroll
        for (int r = 0; r < 4; ++r) {
            const int o = mt*16 + kb*4 + r;
            const float bias = s_bf[o];
            #pragma unroll
            for (int nt = 0; nt < 4; ++nt)
                ob[(size_t)o * HW + (size_t)(y0 + nt) * WW + x0 + cl] = acc[nt][mt][r] + bias;
        }
    }
}

extern "C" void kernel_launch(void* const* d_in, const int* in_sizes, int n_in,
                              void* d_out, int out_size, void* d_ws, size_t ws_size,
                              hipStream_t stream) {
    const float* hs      = (const float*)d_in[0];
    const float* refLR   = (const float*)d_in[1];
    const float* w_first = (const float*)d_in[2];
    const float* b_first = (const float*)d_in[3];
    const float* w_fuse  = (const float*)d_in[4];
    const float* b_fuse  = (const float*)d_in[5];
    float* out = (float*)d_out;

    corr_v6_kernel<<<dim3(2048), dim3(256), 0, stream>>>(hs, refLR, w_first, b_first,
                                                         w_fuse, b_fuse, out);
}

// Round 7
// 228.077 us; speedup vs baseline: 1.2659x; 1.2659x over previous
//
#include <hip/hip_runtime.h>

// B=8, C=64, H=256, W=256
#define BB 8
#define CC 64
#define HH 256
#define WW 256
#define HW (HH*WW)

typedef __attribute__((ext_vector_type(8))) short bf16x8;
typedef __attribute__((ext_vector_type(4))) float f32x4;
typedef __attribute__((ext_vector_type(2))) float f32x2;

__device__ __forceinline__ int reflect_idx(int v, int n) {
    // jnp.pad mode='reflect': -1 -> 1, n -> n-2
    if (v < 0) v = -v;
    if (v >= n) v = 2*n - 2 - v;
    return v;
}

// f32 -> bf16 (RNE) raw bits
__device__ __forceinline__ short f2bf(float f) {
    union { float f; unsigned u; } x; x.f = f;
    unsigned r = (x.u + 0x7fffu + ((x.u >> 16) & 1u)) >> 16;
    return (short)r;
}

__device__ __forceinline__ unsigned cvt_pk_bf16(float lo, float hi) {
    unsigned r;
    asm("v_cvt_pk_bf16_f32 %0, %1, %2" : "=v"(r) : "v"(lo), "v"(hi));
    return r;
}

__global__ __launch_bounds__(256, 4)
void corr_v7_kernel(const float* __restrict__ hs,
                    const float* __restrict__ refLR,
                    const float* __restrict__ w_first,
                    const float* __restrict__ b_first,
                    const float* __restrict__ w_fuse,
                    const float* __restrict__ b_fuse,
                    float* __restrict__ out)
{
    // s_w: bf16 w_fuse, logical layout [o 64][k' 128], k' = g*32+i:
    //      i<16 -> att col g*16+i ; i>=16 -> hs col 48+g*16+i.
    //      16B-granule XOR swizzle: granule' = granule ^ (row&15)  -> b128 reads at 4/bank floor
    __shared__ short s_w[64 * 128];        // 16384 B
    // s_fused (per wave): [pix 64][32 shorts = att16|hs16 of group g],
    //      granule' = granule ^ ((row>>1)&3) -> ~2-way reads & writes
    __shared__ short s_fused[4][64 * 32];  // 16384 B
    // p = hs*ref halo buffers, halo row stride 12 (starts mod16 = 0,12,8,4 -> 2x/bank)
    __shared__ float s_p01[4][240];        // 3840 B
    __shared__ float s_p23[4][240];        // 3840 B  -> total 40448 B: 4 blocks/CU

    const int t = threadIdx.x;
    const int wv = t >> 6, lane = t & 63;

    // XCD swizzle: each XCD owns one batch image (identical to R3)
    const int d = (int)blockIdx.x;
    const int lid = (d & 7) * 256 + (d >> 3);
    const int bx = lid & 15, by = (lid >> 4) & 15, b = lid >> 8;

    // ---- stage swizzled bf16 weights ----
    #pragma unroll
    for (int rep = 0; rep < 32; ++rep) {
        int idx = t + rep * 256;               // m*128 + k'
        int m = idx >> 7, k = idx & 127;
        int g = k >> 5, i = k & 31;
        int src = (i < 16) ? (g * 16 + i) : (48 + g * 16 + i);
        int swz = ((((k >> 3) ^ m) & 15) << 3) | (k & 7);
        s_w[m * 128 + swz] = f2bf(w_fuse[m * 128 + src]);
    }
    __syncthreads();   // only block barrier

    // ---- wave tile: 8x8 pixels; block tile 16x16 (2x2 waves) ----
    const int wy = (wv >> 1) * 8, wx = (wv & 1) * 8;
    const int y0 = by * 16 + wy, x0 = bx * 16 + wx;

    // halo: 10x10 = 100 positions; lane owns pos lane (+ 64+lane if lane<36)
    const bool has1 = lane < 36;
    int g0, g1;
    {
        const int py = lane / 10, px = lane % 10;
        g0 = reflect_idx(y0 + py - 1, HH) * WW + reflect_idx(x0 + px - 1, WW);
    }
    const int l1 = 64 + lane;
    {
        const int py = l1 / 10, px = l1 % 10;
        const int gt = reflect_idx(y0 + py - 1, HH) * WW + reflect_idx(x0 + px - 1, WW);
        g1 = has1 ? gt : g0;
    }
    // LDS p-buffer positions (row stride 12)
    const int pos0 = (lane / 10) * 12 + lane % 10;
    const int pos1 = (l1 / 10) * 12 + l1 % 10;

    const int pyc = lane >> 3, pxc = lane & 7;       // this lane's pixel
    const int gc = (y0 + pyc) * WW + (x0 + pxc);

    // refLR halo values in registers (loaded once)
    const float* rb = refLR + (size_t)b * 9 * HW;
    float rin0[9], rin1[9];
    #pragma unroll
    for (int j = 0; j < 9; ++j) rin0[j] = rb[(size_t)j * HW + g0];
    #pragma unroll
    for (int j = 0; j < 9; ++j) rin1[j] = rb[(size_t)j * HW + g1];

    // accumulators (bias-initialized). C/D: col=lane&15, row=(lane>>4)*4+r
    const int cl = lane & 15, kb = lane >> 4;
    f32x4 acc[4][4];
    #pragma unroll
    for (int mt = 0; mt < 4; ++mt) {
        #pragma unroll
        for (int r = 0; r < 4; ++r) {
            const float bv = b_fuse[mt * 16 + kb * 4 + r];
            #pragma unroll
            for (int nt = 0; nt < 4; ++nt) acc[mt][nt][r] = bv;
        }
    }

    const float* hsb = hs + (size_t)b * CC * HW;
    float* const sp01 = s_p01[wv];
    float* const sp23 = s_p23[wv];
    short* const sfw  = s_fused[wv];
    const int pb = (pyc * 12 + pxc) * 2;     // box-window base (float index)
    const int skey = (lane >> 1) & 3;        // s_fused write swizzle key

    // prefetch chunk 0 hs values
    float h0[4], h1[4], hc[4];
    #pragma unroll
    for (int cc = 0; cc < 4; ++cc) {
        const float* hp = hsb + (size_t)cc * HW;
        h0[cc] = hp[g0]; h1[cc] = hp[g1]; hc[cc] = hp[gc];
    }

    #pragma unroll 1
    for (int ch = 0; ch < 16; ++ch) {
        const int c0 = ch * 4;

        // ref 1x1 conv + leaky + p-products at owned halo positions
        float pr0[4], pr1[4], hcv[4];
        #pragma unroll
        for (int cc = 0; cc < 4; ++cc) {
            const int c = c0 + cc;
            float v0 = b_first[c], v1 = v0;
            #pragma unroll
            for (int j = 0; j < 9; ++j) {
                const float w = w_first[c * 9 + j];   // wave-uniform (s_load)
                v0 = fmaf(w, rin0[j], v0);
                v1 = fmaf(w, rin1[j], v1);
            }
            v0 = v0 > 0.f ? v0 : 0.1f * v0;
            v1 = v1 > 0.f ? v1 : 0.1f * v1;
            pr0[cc] = h0[cc] * v0;
            pr1[cc] = h1[cc] * v1;
            hcv[cc] = hc[cc];
        }
        *(f32x2*)&sp01[pos0 * 2] = (f32x2){pr0[0], pr0[1]};
        *(f32x2*)&sp23[pos0 * 2] = (f32x2){pr0[2], pr0[3]};
        if (has1) {
            *(f32x2*)&sp01[pos1 * 2] = (f32x2){pr1[0], pr1[1]};
            *(f32x2*)&sp23[pos1 * 2] = (f32x2){pr1[2], pr1[3]};
        }
        // wave-local LDS RAW fence (data is wave-private; no s_barrier)
        asm volatile("s_waitcnt lgkmcnt(0)" ::: "memory");

        // 3x3 box-sum of p
        f32x2 a01 = (f32x2){0.f, 0.f}, a23 = (f32x2){0.f, 0.f};
        #pragma unroll
        for (int dy = 0; dy < 3; ++dy)
            #pragma unroll
            for (int dx = 0; dx < 3; ++dx) {
                const int o = pb + (dy * 12 + dx) * 2;
                a01 += *(const f32x2*)&sp01[o];
                a23 += *(const f32x2*)&sp23[o];
            }

        // issue next chunk's hs loads (hidden under sigmoid/MFMA/next conv)
        {
            const int cn = ((ch + 1) & 15) * 4;
            #pragma unroll
            for (int cc = 0; cc < 4; ++cc) {
                const float* hp = hsb + (size_t)(cn + cc) * HW;
                h0[cc] = hp[g0]; h1[cc] = hp[g1]; hc[cc] = hp[gc];
            }
        }

        // sigmoid gate, bf16 pack, write k-slice of fused (swizzled)
        const float cr[4] = {a01[0], a01[1], a23[0], a23[1]};
        float av[4];
        #pragma unroll
        for (int cc = 0; cc < 4; ++cc)
            av[cc] = __builtin_amdgcn_rcpf(
                1.0f + __builtin_amdgcn_exp2f(cr[cc] * -1.44269504088896f)) * hcv[cc];
        uint2 ua, uh;
        ua.x = cvt_pk_bf16(av[0], av[1]);
        ua.y = cvt_pk_bf16(av[2], av[3]);
        uh.x = cvt_pk_bf16(hcv[0], hcv[1]);
        uh.y = cvt_pk_bf16(hcv[2], hcv[3]);
        const int k4 = (ch & 3) * 4;                       // shorts within att half
        const int ga = (ch & 3) >> 1;                      // att granule (0..1)
        const int oa = k4 & 7;                             // offset in granule
        *(uint2*)&sfw[lane * 32 + ((ga       ^ skey) << 3) + oa] = ua;
        *(uint2*)&sfw[lane * 32 + (((2 + ga) ^ skey) << 3) + oa] = uh;

        // group boundary: one k=32 MFMA slice, accumulate
        if ((ch & 3) == 3) {
            asm volatile("s_waitcnt lgkmcnt(0)" ::: "memory");
            const int g = ch >> 2;
            #pragma unroll
            for (int nt = 0; nt < 4; ++nt) {
                const int p = nt * 16 + cl;
                const bf16x8 bf = *(const bf16x8*)
                    &sfw[p * 32 + ((kb ^ ((p >> 1) & 3)) << 3)];
                #pragma unroll
                for (int mt = 0; mt < 4; ++mt) {
                    const bf16x8 af = *(const bf16x8*)
                        &s_w[(mt * 16 + cl) * 128 + (((g * 4 + kb) ^ cl) << 3)];
                    acc[mt][nt] = __builtin_amdgcn_mfma_f32_16x16x32_bf16(af, bf, acc[mt][nt], 0, 0, 0);
                }
            }
        }
    }

    // ---- epilogue: store (identical to R3) ----
    float* const ob = out + (size_t)b * CC * HW;
    #pragma unroll
    for (int mt = 0; mt < 4; ++mt) {
        const int o0 = mt * 16 + kb * 4;
        #pragma unroll
        for (int nt = 0; nt < 4; ++nt) {
            const int p = nt * 16 + cl;           // pixel index in 8x8 tile
            float* op = ob + (size_t)o0 * HW + (size_t)(y0 + (p >> 3)) * WW + (x0 + (p & 7));
            #pragma unroll
            for (int r = 0; r < 4; ++r) op[(size_t)r * HW] = acc[mt][nt][r];
        }
    }
}

extern "C" void kernel_launch(void* const* d_in, const int* in_sizes, int n_in,
                              void* d_out, int out_size, void* d_ws, size_t ws_size,
                              hipStream_t stream) {
    const float* hs      = (const float*)d_in[0];
    const float* refLR   = (const float*)d_in[1];
    const float* w_first = (const float*)d_in[2];
    const float* b_first = (const float*)d_in[3];
    const float* w_fuse  = (const float*)d_in[4];
    const float* b_fuse  = (const float*)d_in[5];
    float* out = (float*)d_out;

    corr_v7_kernel<<<dim3(2048), dim3(256), 0, stream>>>(hs, refLR, w_first, b_first,
                                                         w_fuse, b_fuse, out);
}

// Round 8
// 106.256 us; speedup vs baseline: 2.7172x; 2.1465x over previous
//
#include <hip/hip_runtime.h>

// B=8, C=64, H=256, W=256
#define BB 8
#define CC 64
#define HH 256
#define WW 256
#define HW (HH*WW)

typedef __attribute__((ext_vector_type(8))) short bf16x8;
typedef __attribute__((ext_vector_type(4))) float f32x4;
typedef __attribute__((ext_vector_type(2))) float f32x2;

__device__ __forceinline__ int reflect_idx(int v, int n) {
    // jnp.pad mode='reflect': -1 -> 1, n -> n-2
    if (v < 0) v = -v;
    if (v >= n) v = 2*n - 2 - v;
    return v;
}

// f32 -> bf16 (RNE) raw bits
__device__ __forceinline__ short f2bf(float f) {
    union { float f; unsigned u; } x; x.f = f;
    unsigned r = (x.u + 0x7fffu + ((x.u >> 16) & 1u)) >> 16;
    return (short)r;
}

__device__ __forceinline__ unsigned cvt_pk_bf16(float lo, float hi) {
    unsigned r;
    asm("v_cvt_pk_bf16_f32 %0, %1, %2" : "=v"(r) : "v"(lo), "v"(hi));
    return r;
}

__global__ __launch_bounds__(256, 3)
void corr_v8_kernel(const float* __restrict__ hs,
                    const float* __restrict__ refLR,
                    const float* __restrict__ w_first,
                    const float* __restrict__ b_first,
                    const float* __restrict__ w_fuse,
                    const float* __restrict__ b_fuse,
                    float* __restrict__ out)
{
    // s_w: reordered bf16 w_fuse [o 64][k' 128 pad 136]; k' = g*32+i,
    //      i<16 -> att col g*16+i, i>=16 -> hs col 48+g*16+i   (R3 layout, verified optimal)
    __shared__ short s_w[64 * 136];            // 17408 B
    __shared__ short s_fused[4][64 * 40];      // 20480 B per-wave [pix 64][k 32 pad 40]
    __shared__ float s_p01[4][216];            // p=hs*ref ch0,1 at 108 halo pos (6x18)
    __shared__ float s_p23[4][216];            // ch2,3       -> total 44800 B: 3 blk/CU

    const int t = threadIdx.x;
    const int wv = t >> 6, lane = t & 63;

    // XCD swizzle: each XCD owns one batch image (identical to R3)
    const int d = (int)blockIdx.x;
    const int lid = (d & 7) * 256 + (d >> 3);
    const int bx = lid & 15, by = (lid >> 4) & 15, b = lid >> 8;

    // ---- stage reordered bf16 weights (identical to R3) ----
    #pragma unroll
    for (int rep = 0; rep < 32; ++rep) {
        int idx = t + rep * 256;              // m*128 + k'
        int m = idx >> 7, kp = idx & 127;
        int g = kp >> 5, i = kp & 31;
        int src = (i < 16) ? (g * 16 + i) : (48 + g * 16 + i);
        s_w[m * 136 + kp] = f2bf(w_fuse[m * 128 + src]);
    }
    __syncthreads();   // the only block barrier

    // ---- wave strip: 4 rows x 16 cols within the 16x16 block tile ----
    const int y0 = by * 16 + wv * 4;
    const int x0 = bx * 16;

    // halo: 6 rows x 18 cols = 108 positions; lane owns pos=lane (+ 64+lane if lane<44)
    const bool has1 = lane < 44;
    int g0, g1;
    {
        const int py = lane / 18, px = lane % 18;
        g0 = reflect_idx(y0 + py - 1, HH) * WW + reflect_idx(x0 + px - 1, WW);
    }
    {
        const int pp = 64 + lane;
        const int py = pp / 18, px = pp % 18;
        const int gt = reflect_idx(y0 + py - 1, HH) * WW + reflect_idx(x0 + px - 1, WW);
        g1 = has1 ? gt : g0;
    }
    // lane's own pixel: row pyc (0..3), col pxc (0..15); note pixel index in strip == lane
    const int pyc = lane >> 4, pxc = lane & 15;
    const int gc = (y0 + pyc) * WW + (x0 + pxc);

    // refLR halo values in registers (loaded once)
    const float* rb = refLR + (size_t)b * 9 * HW;
    float rin0[9], rin1[9];
    #pragma unroll
    for (int j = 0; j < 9; ++j) rin0[j] = rb[(size_t)j * HW + g0];
    #pragma unroll
    for (int j = 0; j < 9; ++j) rin1[j] = rb[(size_t)j * HW + g1];

    // accumulators (bias-initialized). C/D: col=lane&15 (pixel), row=(lane>>4)*4+r (out-ch)
    const int cl = lane & 15, kb = lane >> 4;
    f32x4 acc[4][4];
    #pragma unroll
    for (int mt = 0; mt < 4; ++mt) {
        #pragma unroll
        for (int r = 0; r < 4; ++r) {
            const float bv = b_fuse[mt * 16 + kb * 4 + r];
            #pragma unroll
            for (int nt = 0; nt < 4; ++nt) acc[mt][nt][r] = bv;
        }
    }

    const float* hsb = hs + (size_t)b * CC * HW;
    float* const sp01 = s_p01[wv];
    float* const sp23 = s_p23[wv];
    short* const sfw  = s_fused[wv];
    const int pb = (pyc * 18 + pxc) * 2;   // box-window base (float index, row stride 18)

    // prefetch chunk 0 hs values
    float h0[4], h1[4], hc[4];
    #pragma unroll
    for (int cc = 0; cc < 4; ++cc) {
        const float* hp = hsb + (size_t)cc * HW;
        h0[cc] = hp[g0]; h1[cc] = hp[g1]; hc[cc] = hp[gc];
    }

    #pragma unroll 1
    for (int ch = 0; ch < 16; ++ch) {
        const int c0 = ch * 4;

        // ref 1x1 conv + leaky + p-products at owned halo positions
        float pr0[4], pr1[4], hcv[4];
        #pragma unroll
        for (int cc = 0; cc < 4; ++cc) {
            const int c = c0 + cc;
            float v0 = b_first[c], v1 = v0;
            #pragma unroll
            for (int j = 0; j < 9; ++j) {
                const float w = w_first[c * 9 + j];   // wave-uniform (s_load)
                v0 = fmaf(w, rin0[j], v0);
                v1 = fmaf(w, rin1[j], v1);
            }
            v0 = v0 > 0.f ? v0 : 0.1f * v0;
            v1 = v1 > 0.f ? v1 : 0.1f * v1;
            pr0[cc] = h0[cc] * v0;
            pr1[cc] = h1[cc] * v1;
            hcv[cc] = hc[cc];
        }
        *(f32x2*)&sp01[lane * 2] = (f32x2){pr0[0], pr0[1]};
        *(f32x2*)&sp23[lane * 2] = (f32x2){pr0[2], pr0[3]};
        if (has1) {
            *(f32x2*)&sp01[(64 + lane) * 2] = (f32x2){pr1[0], pr1[1]};
            *(f32x2*)&sp23[(64 + lane) * 2] = (f32x2){pr1[2], pr1[3]};
        }
        // wave-local LDS RAW fence (data is wave-private; no s_barrier)
        asm volatile("s_waitcnt lgkmcnt(0)" ::: "memory");

        // 3x3 box-sum of p (row stride 18 -> provably flat bank profile)
        f32x2 a01 = (f32x2){0.f, 0.f}, a23 = (f32x2){0.f, 0.f};
        #pragma unroll
        for (int dy = 0; dy < 3; ++dy)
            #pragma unroll
            for (int dx = 0; dx < 3; ++dx) {
                const int o = pb + (dy * 18 + dx) * 2;
                a01 += *(const f32x2*)&sp01[o];
                a23 += *(const f32x2*)&sp23[o];
            }

        // issue next chunk's hs loads (hidden under sigmoid/MFMA/next conv)
        {
            const int cn = ((ch + 1) & 15) * 4;
            #pragma unroll
            for (int cc = 0; cc < 4; ++cc) {
                const float* hp = hsb + (size_t)(cn + cc) * HW;
                h0[cc] = hp[g0]; h1[cc] = hp[g1]; hc[cc] = hp[gc];
            }
        }

        // sigmoid gate, bf16 pack, write k-slice of fused (R3 layout, stride 40)
        const float cr[4] = {a01[0], a01[1], a23[0], a23[1]};
        float av[4];
        #pragma unroll
        for (int cc = 0; cc < 4; ++cc)
            av[cc] = __builtin_amdgcn_rcpf(
                1.0f + __builtin_amdgcn_exp2f(cr[cc] * -1.44269504088896f)) * hcv[cc];
        uint2 ua, uh;
        ua.x = cvt_pk_bf16(av[0], av[1]);
        ua.y = cvt_pk_bf16(av[2], av[3]);
        uh.x = cvt_pk_bf16(hcv[0], hcv[1]);
        uh.y = cvt_pk_bf16(hcv[2], hcv[3]);
        const int k4 = (ch & 3) * 4;
        *(uint2*)&sfw[lane * 40 + k4]      = ua;   // att*hs at k = k4..k4+3
        *(uint2*)&sfw[lane * 40 + 16 + k4] = uh;   // hs     at k = 16+k4..

        // group boundary: one k=32 MFMA slice, accumulate (identical to R3)
        if ((ch & 3) == 3) {
            asm volatile("s_waitcnt lgkmcnt(0)" ::: "memory");
            const int g = ch >> 2;
            #pragma unroll
            for (int nt = 0; nt < 4; ++nt) {
                const bf16x8 bf = *(const bf16x8*)&sfw[(nt * 16 + cl) * 40 + kb * 8];
                #pragma unroll
                for (int mt = 0; mt < 4; ++mt) {
                    const bf16x8 af = *(const bf16x8*)&s_w[(mt * 16 + cl) * 136 + g * 32 + kb * 8];
                    acc[mt][nt] = __builtin_amdgcn_mfma_f32_16x16x32_bf16(af, bf, acc[mt][nt], 0, 0, 0);
                }
            }
        }
    }

    // ---- epilogue: every store instruction = 4 channel-planes x full 64B lines ----
    float* const ob = out + (size_t)b * CC * HW;
    #pragma unroll
    for (int mt = 0; mt < 4; ++mt) {
        #pragma unroll
        for (int nt = 0; nt < 4; ++nt) {
            #pragma unroll
            for (int r = 0; r < 4; ++r) {
                const int o = mt * 16 + kb * 4 + r;
                ob[(size_t)o * HW + (size_t)(y0 + nt) * WW + (x0 + cl)] = acc[mt][nt][r];
            }
        }
    }
}

extern "C" void kernel_launch(void* const* d_in, const int* in_sizes, int n_in,
                              void* d_out, int out_size, void* d_ws, size_t ws_size,
                              hipStream_t stream) {
    const float* hs      = (const float*)d_in[0];
    const float* refLR   = (const float*)d_in[1];
    const float* w_first = (const float*)d_in[2];
    const float* b_first = (const float*)d_in[3];
    const float* w_fuse  = (const float*)d_in[4];
    const float* b_fuse  = (const float*)d_in[5];
    float* out = (float*)d_out;

    corr_v8_kernel<<<dim3(2048), dim3(256), 0, stream>>>(hs, refLR, w_first, b_first,
                                                         w_fuse, b_fuse, out);
}